// Round 5
// baseline (334.006 us; speedup 1.0000x reference)
//
#include <hip/hip_runtime.h>
#include <math.h>

#define BB 2
#define SS 2048
#define DD 1024
#define HH 16
#define DKK 64
#define MM (BB * SS) /* 4096 */
#define KK DD        /* GEMM K = 1024 */

typedef __attribute__((ext_vector_type(8))) short short8;
typedef __attribute__((ext_vector_type(4))) float floatx4;

__device__ inline unsigned short f2bf(float x) {
    unsigned int u = __float_as_uint(x);
    u += 0x7fffu + ((u >> 16) & 1u);   // round to nearest even
    return (unsigned short)(u >> 16);
}

__device__ inline void cast4f(const float* __restrict__ in, unsigned short* __restrict__ out, int i) {
    const float4 v = *(const float4*)(in + i);
    unsigned long long pk = (unsigned long long)f2bf(v.x)
                          | ((unsigned long long)f2bf(v.y) << 16)
                          | ((unsigned long long)f2bf(v.z) << 32)
                          | ((unsigned long long)f2bf(v.w) << 48);
    *(unsigned long long*)(out + i) = pk;
}

__global__ __launch_bounds__(256) void cast3(const float* __restrict__ a, const float* __restrict__ b,
                                             const float* __restrict__ c,
                                             unsigned short* __restrict__ oa, unsigned short* __restrict__ ob,
                                             unsigned short* __restrict__ oc) {
    const int w = blockIdx.y;
    const float* in = (w == 0) ? a : (w == 1) ? b : c;
    unsigned short* out = (w == 0) ? oa : (w == 1) ? ob : oc;
    cast4f(in, out, (blockIdx.x * 256 + threadIdx.x) * 4);
}

__global__ __launch_bounds__(256) void cast4w(const float* __restrict__ a, const float* __restrict__ b,
                                              const float* __restrict__ c, const float* __restrict__ d,
                                              unsigned short* __restrict__ oa, unsigned short* __restrict__ ob,
                                              unsigned short* __restrict__ oc, unsigned short* __restrict__ od) {
    const int w = blockIdx.y;
    const float* in = (w == 0) ? a : (w == 1) ? b : (w == 2) ? c : d;
    unsigned short* out = (w == 0) ? oa : (w == 1) ? ob : (w == 2) ? oc : od;
    cast4f(in, out, (blockIdx.x * 256 + threadIdx.x) * 4);
}

#define GLDS(gp, lp) __builtin_amdgcn_global_load_lds( \
    (const __attribute__((address_space(1))) void*)(gp), \
    (__attribute__((address_space(3))) void*)(lp), 16, 0, 0)

// 64(M)x128(N) tile, BK=32, dbuf LDS, XOR-swizzled k-segments.
__device__ __forceinline__ void gemm_body(const unsigned short* __restrict__ A,
                                          const unsigned short* __restrict__ W,
                                          const float* __restrict__ bias,
                                          void* __restrict__ Cout, int mode, int blk,
                                          unsigned short* As, unsigned short* Bs) {
    const int t    = threadIdx.x;
    const int lane = t & 63;
    const int wave = t >> 6;
    const int col  = lane & 15;
    const int quad = lane >> 4;

    const int m0  = (blk & 63) * 64;
    const int n0  = (blk >> 6) * 128;
    const int wm0 = (wave & 1) * 32;
    const int wn0 = (wave >> 1) * 64;

    const int sw = ((t & 3) ^ ((t >> 3) & 3)) * 8;
    const size_t arow = (size_t)(m0 + (t >> 2)) * KK + sw;
    const size_t brow = (size_t)(n0 + (t >> 2)) * KK + sw;
    const int rseg = (quad ^ ((col >> 1) & 3)) * 8;

    floatx4 acc[2][4] = {};

    GLDS(A + arow,           &As[(t >> 2) * 32 + sw]);
    GLDS(W + brow,           &Bs[(t >> 2) * 32 + sw]);
    GLDS(W + brow + 64 * KK, &Bs[(64 + (t >> 2)) * 32 + sw]);

    int cur = 0;
    for (int kb = 0; kb < KK / 32; ++kb) {
        __syncthreads();

        if (kb + 1 < KK / 32) {
            const int k0 = (kb + 1) * 32;
            const int nx = cur ^ 1;
            GLDS(A + arow + k0,           &As[nx * 64 * 32 + (t >> 2) * 32 + sw]);
            GLDS(W + brow + k0,           &Bs[nx * 128 * 32 + (t >> 2) * 32 + sw]);
            GLDS(W + brow + k0 + 64 * KK, &Bs[nx * 128 * 32 + (64 + (t >> 2)) * 32 + sw]);
        }

        const unsigned short* Ab = &As[cur * 64 * 32];
        const unsigned short* Bb = &Bs[cur * 128 * 32];
        short8 a[2], b[4];
        #pragma unroll
        for (int i = 0; i < 2; ++i)
            a[i] = *(const short8*)(Ab + (wm0 + i * 16 + col) * 32 + rseg);
        #pragma unroll
        for (int j = 0; j < 4; ++j)
            b[j] = *(const short8*)(Bb + (wn0 + j * 16 + col) * 32 + rseg);

        #pragma unroll
        for (int i = 0; i < 2; ++i)
            #pragma unroll
            for (int j = 0; j < 4; ++j)
                acc[i][j] = __builtin_amdgcn_mfma_f32_16x16x32_bf16(a[i], b[j], acc[i][j], 0, 0, 0);

        cur ^= 1;
    }

    #pragma unroll
    for (int i = 0; i < 2; ++i) {
        #pragma unroll
        for (int j = 0; j < 4; ++j) {
            const int n  = n0 + wn0 + j * 16 + col;
            const float bv = bias[n];
            const int h = n / DKK, dk = n % DKK;
            #pragma unroll
            for (int r = 0; r < 4; ++r) {
                const int m = m0 + wm0 + i * 16 + quad * 4 + r;
                const int bdx = m / SS, s = m % SS;
                const float v = acc[i][j][r] + bv;
                if (mode == 0) {
                    ((unsigned short*)Cout)[(((size_t)(bdx * HH + h)) * SS + s) * DKK + dk] = f2bf(v);
                } else if (mode == 1) {
                    ((unsigned short*)Cout)[(((size_t)(bdx * HH + h)) * DKK + dk) * SS + s] = f2bf(v);
                } else {
                    ((float*)Cout)[(size_t)m * DD + n] = v;
                }
            }
        }
    }
}

// fused Q/K/V projections: 1536 blocks (3 x 512) -> 6 blocks/CU overlap
__global__ __launch_bounds__(256) void gemm_qkv(const unsigned short* __restrict__ qB,
                                                const unsigned short* __restrict__ kB,
                                                const unsigned short* __restrict__ vB,
                                                const unsigned short* __restrict__ wqB,
                                                const unsigned short* __restrict__ wkB,
                                                const unsigned short* __restrict__ wvB,
                                                const float* __restrict__ bq,
                                                const float* __restrict__ bk,
                                                const float* __restrict__ bv,
                                                unsigned short* __restrict__ Qh,
                                                unsigned short* __restrict__ Kh,
                                                unsigned short* __restrict__ Vt) {
    __shared__ __align__(16) unsigned short As[2 * 64 * 32];
    __shared__ __align__(16) unsigned short Bs[2 * 128 * 32];
    const int which = blockIdx.x >> 9;
    const int blk   = blockIdx.x & 511;
    if (which == 0)      gemm_body(qB, wqB, bq, Qh, 0, blk, As, Bs);
    else if (which == 1) gemm_body(kB, wkB, bk, Kh, 0, blk, As, Bs);
    else                 gemm_body(vB, wvB, bv, Vt, 1, blk, As, Bs);
}

__global__ __launch_bounds__(256) void gemm_out(const unsigned short* __restrict__ A,
                                                const unsigned short* __restrict__ W,
                                                const float* __restrict__ bias,
                                                float* __restrict__ C) {
    __shared__ __align__(16) unsigned short As[2 * 64 * 32];
    __shared__ __align__(16) unsigned short Bs[2 * 128 * 32];
    gemm_body(A, W, bias, C, 2, blockIdx.x, As, Bs);
}

// ---- attention ----
#define C1 0.18033688011112042f   /* 0.125 * log2(e) */
#define C2 11.541560327111707f    /* 8 * log2(e)     */

__device__ __forceinline__ void attn_block(int j0, int q0, bool needMask,
                                           const short8& qa0, const short8& qa1,
                                           const short8& k0, const short8& k1,
                                           const short8& k2, const short8& k3,
                                           const short8& v0, const short8& v1,
                                           const short8& v2, const short8& v3,
                                           unsigned short* Pw, int col, int quad,
                                           floatx4& o0, floatx4& o1, floatx4& o2, floatx4& o3,
                                           float* lp) {
    floatx4 s0 = {0.f, 0.f, 0.f, 0.f}, s1 = s0;
    s0 = __builtin_amdgcn_mfma_f32_16x16x32_bf16(qa0, k0, s0, 0, 0, 0);
    s0 = __builtin_amdgcn_mfma_f32_16x16x32_bf16(qa1, k1, s0, 0, 0, 0);
    s1 = __builtin_amdgcn_mfma_f32_16x16x32_bf16(qa0, k2, s1, 0, 0, 0);
    s1 = __builtin_amdgcn_mfma_f32_16x16x32_bf16(qa1, k3, s1, 0, 0, 0);

    if (needMask) {
        #pragma unroll
        for (int r = 0; r < 4; ++r) {
            const int row = q0 + quad * 4 + r;
            const float p0 = (j0 + col      <= row) ? __builtin_exp2f(fmaf(s0[r], C1, -C2)) : 0.f;
            const float p1 = (j0 + 16 + col <= row) ? __builtin_exp2f(fmaf(s1[r], C1, -C2)) : 0.f;
            lp[r] += p0 + p1;
            Pw[(quad * 4 + r) * 40 + col]      = f2bf(p0);
            Pw[(quad * 4 + r) * 40 + col + 16] = f2bf(p1);
        }
    } else {
        #pragma unroll
        for (int r = 0; r < 4; ++r) {
            const float p0 = __builtin_exp2f(fmaf(s0[r], C1, -C2));
            const float p1 = __builtin_exp2f(fmaf(s1[r], C1, -C2));
            lp[r] += p0 + p1;
            Pw[(quad * 4 + r) * 40 + col]      = f2bf(p0);
            Pw[(quad * 4 + r) * 40 + col + 16] = f2bf(p1);
        }
    }

    const short8 pa = *(const short8*)(Pw + col * 40 + quad * 8);

    o0 = __builtin_amdgcn_mfma_f32_16x16x32_bf16(pa, v0, o0, 0, 0, 0);
    o1 = __builtin_amdgcn_mfma_f32_16x16x32_bf16(pa, v1, o1, 0, 0, 0);
    o2 = __builtin_amdgcn_mfma_f32_16x16x32_bf16(pa, v2, o2, 0, 0, 0);
    o3 = __builtin_amdgcn_mfma_f32_16x16x32_bf16(pa, v3, o3, 0, 0, 0);
}

#define LOADKV(kk0, kk1, kk2, kk3, vv0, vv1, vv2, vv3, jj)                      \
    {                                                                           \
        const unsigned short* Kp = Kb + (size_t)((jj) + col) * DKK + quad * 8;  \
        kk0 = *(const short8*)(Kp);                                             \
        kk1 = *(const short8*)(Kp + 32);                                        \
        kk2 = *(const short8*)(Kp + 16 * DKK);                                  \
        kk3 = *(const short8*)(Kp + 16 * DKK + 32);                             \
        const unsigned short* Vp = Vb + (jj) + quad * 8;                        \
        vv0 = *(const short8*)(Vp + (size_t)(col)      * SS);                   \
        vv1 = *(const short8*)(Vp + (size_t)(16 + col) * SS);                   \
        vv2 = *(const short8*)(Vp + (size_t)(32 + col) * SS);                   \
        vv3 = *(const short8*)(Vp + (size_t)(48 + col) * SS);                   \
    }

// One wave = one 16-query tile. 1024 blocks -> 4 blocks/CU (16 waves/CU).
// XCD swizzle: heads {x, x+8, x+16, x+24} on xcd x; block tiles {t,127-t,32+t,95-t}.
__global__ __launch_bounds__(256, 4) void attn_mfma(const unsigned short* __restrict__ Qh,
                                                    const unsigned short* __restrict__ Kh,
                                                    const unsigned short* __restrict__ Vt,
                                                    unsigned short* __restrict__ X) {
    __shared__ unsigned short Plds[4][16 * 40];

    const int lane = threadIdx.x & 63;
    const int wave = threadIdx.x >> 6;
    const int col  = lane & 15;
    const int quad = lane >> 4;

    const int lin = blockIdx.x;
    const int xcd = lin & 7;
    const int rem = lin >> 3;             // 0..127
    const int bh  = xcd + 8 * (rem & 3);  // 0..31
    const int tg  = rem >> 2;             // 0..31
    const int tile = (wave == 0) ? tg : (wave == 1) ? 127 - tg
                   : (wave == 2) ? 32 + tg : 95 - tg;
    const int q0 = tile * 16;
    const int b  = bh / HH, h = bh % HH;

    unsigned short* Pw = &Plds[wave][0];
    const unsigned short* Kb = Kh + (size_t)bh * SS * DKK;
    const unsigned short* Vb = Vt + (size_t)bh * DKK * SS;

    const unsigned short* Qb = Qh + ((size_t)bh * SS + q0) * DKK;
    const short8 qa0 = *(const short8*)(Qb + (size_t)col * DKK + quad * 8);
    const short8 qa1 = *(const short8*)(Qb + (size_t)col * DKK + 32 + quad * 8);

    floatx4 o0 = {0.f, 0.f, 0.f, 0.f}, o1 = o0, o2 = o0, o3 = o0;
    float lp[4] = {0.f, 0.f, 0.f, 0.f};

    const int nkb = (16 * tile + 47) / 32;

    short8 ak0, ak1, ak2, ak3, av0, av1, av2, av3;   // set A
    short8 bk0, bk1, bk2, bk3, bv0, bv1, bv2, bv3;   // set B
    LOADKV(ak0, ak1, ak2, ak3, av0, av1, av2, av3, 0)

    for (int jb = 0; jb < nkb; jb += 2) {
        const int j0 = jb * 32;
        if (jb + 1 < nkb)
            LOADKV(bk0, bk1, bk2, bk3, bv0, bv1, bv2, bv3, j0 + 32)

        attn_block(j0, q0, j0 + 31 > q0, qa0, qa1,
                   ak0, ak1, ak2, ak3, av0, av1, av2, av3,
                   Pw, col, quad, o0, o1, o2, o3, lp);

        if (jb + 1 < nkb) {
            if (jb + 2 < nkb)
                LOADKV(ak0, ak1, ak2, ak3, av0, av1, av2, av3, j0 + 64)

            attn_block(j0 + 32, q0, j0 + 63 > q0, qa0, qa1,
                       bk0, bk1, bk2, bk3, bv0, bv1, bv2, bv3,
                       Pw, col, quad, o0, o1, o2, o3, lp);
        }
    }

    #pragma unroll
    for (int r = 0; r < 4; ++r) {
        float s = lp[r];
        s += __shfl_xor(s, 1, 64);
        s += __shfl_xor(s, 2, 64);
        s += __shfl_xor(s, 4, 64);
        s += __shfl_xor(s, 8, 64);
        lp[r] = 1.f / s;
    }

    unsigned short* Xp = X + ((size_t)(b * SS + q0 + quad * 4)) * DD + h * DKK + col;
    #pragma unroll
    for (int r = 0; r < 4; ++r) {
        Xp[(size_t)r * DD + 0]  = f2bf(o0[r] * lp[r]);
        Xp[(size_t)r * DD + 16] = f2bf(o1[r] * lp[r]);
        Xp[(size_t)r * DD + 32] = f2bf(o2[r] * lp[r]);
        Xp[(size_t)r * DD + 48] = f2bf(o3[r] * lp[r]);
    }
}

extern "C" void kernel_launch(void* const* d_in, const int* in_sizes, int n_in,
                              void* d_out, int out_size, void* d_ws, size_t ws_size,
                              hipStream_t stream) {
    const float* query = (const float*)d_in[0];
    const float* key   = (const float*)d_in[1];
    const float* value = (const float*)d_in[2];
    const float* wq    = (const float*)d_in[3];
    const float* bq    = (const float*)d_in[4];
    const float* wk    = (const float*)d_in[5];
    const float* bk    = (const float*)d_in[6];
    const float* wv    = (const float*)d_in[7];
    const float* bv    = (const float*)d_in[8];
    const float* wo    = (const float*)d_in[9];
    const float* bo    = (const float*)d_in[10];

    char* ws = (char*)d_ws;
    const size_t MB = 1024 * 1024;
    unsigned short* qB  = (unsigned short*)(ws);             // bf16 [4096,1024] 8 MB
    unsigned short* kB  = (unsigned short*)(ws + 8 * MB);
    unsigned short* vB  = (unsigned short*)(ws + 16 * MB);
    unsigned short* wqB = (unsigned short*)(ws + 24 * MB);   // bf16 [1024,1024] 2 MB
    unsigned short* wkB = (unsigned short*)(ws + 26 * MB);
    unsigned short* wvB = (unsigned short*)(ws + 28 * MB);
    unsigned short* woB = (unsigned short*)(ws + 30 * MB);
    unsigned short* Qh  = (unsigned short*)(ws + 32 * MB);   // bf16 [B,H,S,DK] 8 MB
    unsigned short* Kh  = (unsigned short*)(ws + 40 * MB);
    unsigned short* Vt  = (unsigned short*)(ws + 48 * MB);   // bf16 [B,H,DK,S] 8 MB
    unsigned short* Xb  = (unsigned short*)(ws + 56 * MB);   // bf16 [B,S,D]    8 MB

    cast3<<<dim3(4096, 3), 256, 0, stream>>>(query, key, value, qB, kB, vB);
    cast4w<<<dim3(1024, 4), 256, 0, stream>>>(wq, wk, wv, wo, wqB, wkB, wvB, woB);

    gemm_qkv<<<1536, 256, 0, stream>>>(qB, kB, vB, wqB, wkB, wvB, bq, bk, bv, Qh, Kh, Vt);

    attn_mfma<<<1024, 256, 0, stream>>>(Qh, Kh, Vt, Xb);

    gemm_out<<<512, 256, 0, stream>>>(Xb, woB, bo, (float*)d_out);
}

// Round 6
// 310.290 us; speedup vs baseline: 1.0764x; 1.0764x over previous
//
#include <hip/hip_runtime.h>
#include <math.h>

#define BB 2
#define SS 2048
#define DD 1024
#define HH 16
#define DKK 64
#define MM (BB * SS) /* 4096 */
#define KK DD        /* GEMM K = 1024 */

typedef __attribute__((ext_vector_type(8))) short short8;
typedef __attribute__((ext_vector_type(4))) float floatx4;

__device__ inline unsigned short f2bf(float x) {
    unsigned int u = __float_as_uint(x);
    u += 0x7fffu + ((u >> 16) & 1u);   // round to nearest even
    return (unsigned short)(u >> 16);
}

__device__ inline void cast4f(const float* __restrict__ in, unsigned short* __restrict__ out, int i) {
    const float4 v = *(const float4*)(in + i);
    unsigned long long pk = (unsigned long long)f2bf(v.x)
                          | ((unsigned long long)f2bf(v.y) << 16)
                          | ((unsigned long long)f2bf(v.z) << 32)
                          | ((unsigned long long)f2bf(v.w) << 48);
    *(unsigned long long*)(out + i) = pk;
}

__global__ __launch_bounds__(256) void cast3(const float* __restrict__ a, const float* __restrict__ b,
                                             const float* __restrict__ c,
                                             unsigned short* __restrict__ oa, unsigned short* __restrict__ ob,
                                             unsigned short* __restrict__ oc) {
    const int w = blockIdx.y;
    const float* in = (w == 0) ? a : (w == 1) ? b : c;
    unsigned short* out = (w == 0) ? oa : (w == 1) ? ob : oc;
    cast4f(in, out, (blockIdx.x * 256 + threadIdx.x) * 4);
}

__global__ __launch_bounds__(256) void cast4w(const float* __restrict__ a, const float* __restrict__ b,
                                              const float* __restrict__ c, const float* __restrict__ d,
                                              unsigned short* __restrict__ oa, unsigned short* __restrict__ ob,
                                              unsigned short* __restrict__ oc, unsigned short* __restrict__ od) {
    const int w = blockIdx.y;
    const float* in = (w == 0) ? a : (w == 1) ? b : (w == 2) ? c : d;
    unsigned short* out = (w == 0) ? oa : (w == 1) ? ob : (w == 2) ? oc : od;
    cast4f(in, out, (blockIdx.x * 256 + threadIdx.x) * 4);
}

#define GLDS(gp, lp) __builtin_amdgcn_global_load_lds( \
    (const __attribute__((address_space(1))) void*)(gp), \
    (__attribute__((address_space(3))) void*)(lp), 16, 0, 0)

// 64(M)x128(N) tile, BK=32, dbuf LDS, XOR-swizzled k-segments.
__device__ __forceinline__ void gemm_body(const unsigned short* __restrict__ A,
                                          const unsigned short* __restrict__ W,
                                          const float* __restrict__ bias,
                                          void* __restrict__ Cout, int mode, int blk,
                                          unsigned short* As, unsigned short* Bs) {
    const int t    = threadIdx.x;
    const int lane = t & 63;
    const int wave = t >> 6;
    const int col  = lane & 15;
    const int quad = lane >> 4;

    const int m0  = (blk & 63) * 64;
    const int n0  = (blk >> 6) * 128;
    const int wm0 = (wave & 1) * 32;
    const int wn0 = (wave >> 1) * 64;

    const int sw = ((t & 3) ^ ((t >> 3) & 3)) * 8;
    const size_t arow = (size_t)(m0 + (t >> 2)) * KK + sw;
    const size_t brow = (size_t)(n0 + (t >> 2)) * KK + sw;
    const int rseg = (quad ^ ((col >> 1) & 3)) * 8;

    floatx4 acc[2][4] = {};

    GLDS(A + arow,           &As[(t >> 2) * 32 + sw]);
    GLDS(W + brow,           &Bs[(t >> 2) * 32 + sw]);
    GLDS(W + brow + 64 * KK, &Bs[(64 + (t >> 2)) * 32 + sw]);

    int cur = 0;
    for (int kb = 0; kb < KK / 32; ++kb) {
        __syncthreads();

        if (kb + 1 < KK / 32) {
            const int k0 = (kb + 1) * 32;
            const int nx = cur ^ 1;
            GLDS(A + arow + k0,           &As[nx * 64 * 32 + (t >> 2) * 32 + sw]);
            GLDS(W + brow + k0,           &Bs[nx * 128 * 32 + (t >> 2) * 32 + sw]);
            GLDS(W + brow + k0 + 64 * KK, &Bs[nx * 128 * 32 + (64 + (t >> 2)) * 32 + sw]);
        }

        const unsigned short* Ab = &As[cur * 64 * 32];
        const unsigned short* Bb = &Bs[cur * 128 * 32];
        short8 a[2], b[4];
        #pragma unroll
        for (int i = 0; i < 2; ++i)
            a[i] = *(const short8*)(Ab + (wm0 + i * 16 + col) * 32 + rseg);
        #pragma unroll
        for (int j = 0; j < 4; ++j)
            b[j] = *(const short8*)(Bb + (wn0 + j * 16 + col) * 32 + rseg);

        #pragma unroll
        for (int i = 0; i < 2; ++i)
            #pragma unroll
            for (int j = 0; j < 4; ++j)
                acc[i][j] = __builtin_amdgcn_mfma_f32_16x16x32_bf16(a[i], b[j], acc[i][j], 0, 0, 0);

        cur ^= 1;
    }

    #pragma unroll
    for (int i = 0; i < 2; ++i) {
        #pragma unroll
        for (int j = 0; j < 4; ++j) {
            const int n  = n0 + wn0 + j * 16 + col;
            const float bv = bias[n];
            const int h = n / DKK, dk = n % DKK;
            #pragma unroll
            for (int r = 0; r < 4; ++r) {
                const int m = m0 + wm0 + i * 16 + quad * 4 + r;
                const int bdx = m / SS, s = m % SS;
                const float v = acc[i][j][r] + bv;
                if (mode == 0) {
                    ((unsigned short*)Cout)[(((size_t)(bdx * HH + h)) * SS + s) * DKK + dk] = f2bf(v);
                } else if (mode == 1) {
                    ((unsigned short*)Cout)[(((size_t)(bdx * HH + h)) * DKK + dk) * SS + s] = f2bf(v);
                } else {
                    ((float*)Cout)[(size_t)m * DD + n] = v;
                }
            }
        }
    }
}

// fused Q/K/V projections: 1536 blocks (3 x 512) -> 6 blocks/CU overlap
__global__ __launch_bounds__(256) void gemm_qkv(const unsigned short* __restrict__ qB,
                                                const unsigned short* __restrict__ kB,
                                                const unsigned short* __restrict__ vB,
                                                const unsigned short* __restrict__ wqB,
                                                const unsigned short* __restrict__ wkB,
                                                const unsigned short* __restrict__ wvB,
                                                const float* __restrict__ bq,
                                                const float* __restrict__ bk,
                                                const float* __restrict__ bv,
                                                unsigned short* __restrict__ Qh,
                                                unsigned short* __restrict__ Kh,
                                                unsigned short* __restrict__ Vt) {
    __shared__ __align__(16) unsigned short As[2 * 64 * 32];
    __shared__ __align__(16) unsigned short Bs[2 * 128 * 32];
    const int which = blockIdx.x >> 9;
    const int blk   = blockIdx.x & 511;
    if (which == 0)      gemm_body(qB, wqB, bq, Qh, 0, blk, As, Bs);
    else if (which == 1) gemm_body(kB, wkB, bk, Kh, 0, blk, As, Bs);
    else                 gemm_body(vB, wvB, bv, Vt, 1, blk, As, Bs);
}

__global__ __launch_bounds__(256) void gemm_out(const unsigned short* __restrict__ A,
                                                const unsigned short* __restrict__ W,
                                                const float* __restrict__ bias,
                                                float* __restrict__ C) {
    __shared__ __align__(16) unsigned short As[2 * 64 * 32];
    __shared__ __align__(16) unsigned short Bs[2 * 128 * 32];
    gemm_body(A, W, bias, C, 2, blockIdx.x, As, Bs);
}

// ---- attention ----
#define C1 0.18033688011112042f   /* 0.125 * log2(e) */
#define C2 11.541560327111707f    /* 8 * log2(e)     */

#define MFMA __builtin_amdgcn_mfma_f32_16x16x32_bf16

#define LOADK(kk, jj)                                                           \
    {                                                                           \
        const unsigned short* Kp = Kb + (size_t)((jj) + col) * DKK + quad * 8;  \
        kk##0 = *(const short8*)(Kp);                                           \
        kk##1 = *(const short8*)(Kp + 32);                                      \
        kk##2 = *(const short8*)(Kp + 16 * DKK);                                \
        kk##3 = *(const short8*)(Kp + 16 * DKK + 32);                           \
    }

#define LOADV(vv, jj)                                                           \
    {                                                                           \
        const unsigned short* Vp = Vb + (jj) + quad * 8;                        \
        vv##0 = *(const short8*)(Vp + (size_t)(col)      * SS);                 \
        vv##1 = *(const short8*)(Vp + (size_t)(16 + col) * SS);                 \
        vv##2 = *(const short8*)(Vp + (size_t)(32 + col) * SS);                 \
        vv##3 = *(const short8*)(Vp + (size_t)(48 + col) * SS);                 \
    }

#define QK4(sd0, sd1, kk)                       \
    {                                           \
        sd0 = (floatx4){0.f, 0.f, 0.f, 0.f};    \
        sd1 = (floatx4){0.f, 0.f, 0.f, 0.f};    \
        sd0 = MFMA(qa0, kk##0, sd0, 0, 0, 0);   \
        sd0 = MFMA(qa1, kk##1, sd0, 0, 0, 0);   \
        sd1 = MFMA(qa0, kk##2, sd1, 0, 0, 0);   \
        sd1 = MFMA(qa1, kk##3, sd1, 0, 0, 0);   \
    }

// exp + P->LDS (truncating bf16) + pa read + PV accumulate
#define SOFTPV(j0v, vv)                                                                              \
    {                                                                                                \
        if ((j0v) + 31 > q0) {                                                                       \
            _Pragma("unroll")                                                                        \
            for (int r = 0; r < 4; ++r) {                                                            \
                const int row = q0 + quad * 4 + r;                                                   \
                const float p0 = ((j0v) + col      <= row) ? __builtin_exp2f(fmaf(sc0[r], C1, -C2)) : 0.f; \
                const float p1 = ((j0v) + 16 + col <= row) ? __builtin_exp2f(fmaf(sc1[r], C1, -C2)) : 0.f; \
                lp[r] += p0 + p1;                                                                    \
                Pw[(quad * 4 + r) * 40 + col]      = (unsigned short)(__float_as_uint(p0) >> 16);    \
                Pw[(quad * 4 + r) * 40 + col + 16] = (unsigned short)(__float_as_uint(p1) >> 16);    \
            }                                                                                        \
        } else {                                                                                     \
            _Pragma("unroll")                                                                        \
            for (int r = 0; r < 4; ++r) {                                                            \
                const float p0 = __builtin_exp2f(fmaf(sc0[r], C1, -C2));                             \
                const float p1 = __builtin_exp2f(fmaf(sc1[r], C1, -C2));                             \
                lp[r] += p0 + p1;                                                                    \
                Pw[(quad * 4 + r) * 40 + col]      = (unsigned short)(__float_as_uint(p0) >> 16);    \
                Pw[(quad * 4 + r) * 40 + col + 16] = (unsigned short)(__float_as_uint(p1) >> 16);    \
            }                                                                                        \
        }                                                                                            \
        const short8 pa = *(const short8*)(Pw + col * 40 + quad * 8);                                \
        o0 = MFMA(pa, vv##0, o0, 0, 0, 0);                                                           \
        o1 = MFMA(pa, vv##1, o1, 0, 0, 0);                                                           \
        o2 = MFMA(pa, vv##2, o2, 0, 0, 0);                                                           \
        o3 = MFMA(pa, vv##3, o3, 0, 0, 0);                                                           \
    }

// One wave = one 16-query tile. 1024 blocks -> 4 blocks/CU (16 waves/CU).
// Rotated pipeline: QK(j+1) issues before the P LDS round-trip of block j,
// so the MFMA pipe is busy during the lgkm wait; K loads 1 body ahead, V >1.
__global__ __launch_bounds__(256) void attn_mfma(const unsigned short* __restrict__ Qh,
                                                 const unsigned short* __restrict__ Kh,
                                                 const unsigned short* __restrict__ Vt,
                                                 unsigned short* __restrict__ X) {
    __shared__ unsigned short Plds[4][16 * 40];

    const int lane = threadIdx.x & 63;
    const int wave = threadIdx.x >> 6;
    const int col  = lane & 15;
    const int quad = lane >> 4;

    const int lin = blockIdx.x;
    const int xcd = lin & 7;
    const int rem = lin >> 3;             // 0..127
    const int bh  = xcd + 8 * (rem & 3);  // 0..31
    const int tg  = rem >> 2;             // 0..31
    const int tile = (wave == 0) ? tg : (wave == 1) ? 127 - tg
                   : (wave == 2) ? 32 + tg : 95 - tg;
    const int q0 = tile * 16;
    const int b  = bh / HH, h = bh % HH;

    unsigned short* Pw = &Plds[wave][0];
    const unsigned short* Kb = Kh + (size_t)bh * SS * DKK;
    const unsigned short* Vb = Vt + (size_t)bh * DKK * SS;

    const unsigned short* Qb = Qh + ((size_t)bh * SS + q0) * DKK;
    const short8 qa0 = *(const short8*)(Qb + (size_t)col * DKK + quad * 8);
    const short8 qa1 = *(const short8*)(Qb + (size_t)col * DKK + 32 + quad * 8);

    floatx4 o0 = {0.f, 0.f, 0.f, 0.f}, o1 = o0, o2 = o0, o3 = o0;
    float lp[4] = {0.f, 0.f, 0.f, 0.f};

    const int nkb = (16 * tile + 47) / 32;

    short8 kA0, kA1, kA2, kA3, kB0, kB1, kB2, kB3;
    short8 vA0, vA1, vA2, vA3, vB0, vB1, vB2, vB3;
    floatx4 sc0, sc1, sn0, sn1;

    LOADK(kA, 0)
    LOADV(vA, 0)
    if (nkb > 1) LOADK(kB, 32)
    QK4(sc0, sc1, kA)   // kA dead

    for (int jb = 0; jb < nkb; jb += 2) {
        const int j0 = jb * 32;
        // ---- even body: current block jb (V in vA); next K in kB
        if (jb + 1 < nkb) QK4(sn0, sn1, kB)       // kB dead after
        if (jb + 2 < nkb) LOADK(kA, j0 + 64)      // consumed next body
        if (jb + 1 < nkb) LOADV(vB, j0 + 32)      // consumed next body
        SOFTPV(j0, vA)                            // vA dead after
        sc0 = sn0; sc1 = sn1;
        if (jb + 1 >= nkb) break;
        // ---- odd body: current block jb+1 (V in vB); next K in kA
        if (jb + 2 < nkb) QK4(sn0, sn1, kA)
        if (jb + 3 < nkb) LOADK(kB, j0 + 96)
        if (jb + 2 < nkb) LOADV(vA, j0 + 64)
        SOFTPV(j0 + 32, vB)
        sc0 = sn0; sc1 = sn1;
    }

    #pragma unroll
    for (int r = 0; r < 4; ++r) {
        float s = lp[r];
        s += __shfl_xor(s, 1, 64);
        s += __shfl_xor(s, 2, 64);
        s += __shfl_xor(s, 4, 64);
        s += __shfl_xor(s, 8, 64);
        lp[r] = 1.f / s;
    }

    unsigned short* Xp = X + ((size_t)(b * SS + q0 + quad * 4)) * DD + h * DKK + col;
    #pragma unroll
    for (int r = 0; r < 4; ++r) {
        Xp[(size_t)r * DD + 0]  = f2bf(o0[r] * lp[r]);
        Xp[(size_t)r * DD + 16] = f2bf(o1[r] * lp[r]);
        Xp[(size_t)r * DD + 32] = f2bf(o2[r] * lp[r]);
        Xp[(size_t)r * DD + 48] = f2bf(o3[r] * lp[r]);
    }
}

extern "C" void kernel_launch(void* const* d_in, const int* in_sizes, int n_in,
                              void* d_out, int out_size, void* d_ws, size_t ws_size,
                              hipStream_t stream) {
    const float* query = (const float*)d_in[0];
    const float* key   = (const float*)d_in[1];
    const float* value = (const float*)d_in[2];
    const float* wq    = (const float*)d_in[3];
    const float* bq    = (const float*)d_in[4];
    const float* wk    = (const float*)d_in[5];
    const float* bk    = (const float*)d_in[6];
    const float* wv    = (const float*)d_in[7];
    const float* bv    = (const float*)d_in[8];
    const float* wo    = (const float*)d_in[9];
    const float* bo    = (const float*)d_in[10];

    char* ws = (char*)d_ws;
    const size_t MB = 1024 * 1024;
    unsigned short* qB  = (unsigned short*)(ws);             // bf16 [4096,1024] 8 MB
    unsigned short* kB  = (unsigned short*)(ws + 8 * MB);
    unsigned short* vB  = (unsigned short*)(ws + 16 * MB);
    unsigned short* wqB = (unsigned short*)(ws + 24 * MB);   // bf16 [1024,1024] 2 MB
    unsigned short* wkB = (unsigned short*)(ws + 26 * MB);
    unsigned short* wvB = (unsigned short*)(ws + 28 * MB);
    unsigned short* woB = (unsigned short*)(ws + 30 * MB);
    unsigned short* Qh  = (unsigned short*)(ws + 32 * MB);   // bf16 [B,H,S,DK] 8 MB
    unsigned short* Kh  = (unsigned short*)(ws + 40 * MB);
    unsigned short* Vt  = (unsigned short*)(ws + 48 * MB);   // bf16 [B,H,DK,S] 8 MB
    unsigned short* Xb  = (unsigned short*)(ws + 56 * MB);   // bf16 [B,S,D]    8 MB

    cast3<<<dim3(4096, 3), 256, 0, stream>>>(query, key, value, qB, kB, vB);
    cast4w<<<dim3(1024, 4), 256, 0, stream>>>(wq, wk, wv, wo, wqB, wkB, wvB, woB);

    gemm_qkv<<<1536, 256, 0, stream>>>(qB, kB, vB, wqB, wkB, wvB, bq, bk, bv, Qh, Kh, Vt);

    attn_mfma<<<1024, 256, 0, stream>>>(Qh, Kh, Vt, Xb);

    gemm_out<<<512, 256, 0, stream>>>(Xb, woB, bo, (float*)d_out);
}